// Round 4
// baseline (130.157 us; speedup 1.0000x reference)
//
#include <hip/hip_runtime.h>

// KAN conv as densified GEMM: out[px,f] = sum_k Basis[px,k] * W[k,f]
//   px = (b,p,q) 8192, f = 64, K = 16 chunks x 640:
//   chunk kl in [0,576): spline (cl*144 + ij*16 + g), taps (1-fr)@idx, fr@idx+1
//   chunk kl in [576,640): silu at cl*16 + ij (ij<9), rest zero-pad (W rows 0)
// W pre-swizzled to MFMA 16x16x32 f16 B-fragment order.
// THIS REVISION: BARRIER-FREE main loop. The old [scatter->bar->MFMA->bar]
// 2-phase structure carried the classic ~72% lockstep stall (kan ~40us vs
// ~10us L2 floor). Now each lane builds its OWN A-fragment in registers:
// lane (m,kq) needs A[m][kq*8..+8) = 8 consecutive grid slots of ONE
// (px,cl,ij) spline -> one scalar x load + ~30 VALU (two f16 taps packed
// into 4 u32 words). Silu ksteps (18,19 -> wave 3 only) build per-element.
// No basis LDS, no scatter, no ds_read for A, no in-loop barriers: VALU,
// B-loads and MFMA overlap freely across 12 waves/CU.
// LDS only for the final 4-wave reduce (33 KB). Epilogue atomicAdds into out.

typedef _Float16 v8h __attribute__((ext_vector_type(8)));
typedef float    v4f __attribute__((ext_vector_type(4)));
typedef unsigned int u32;
typedef u32      v4u __attribute__((ext_vector_type(4)));

#define NSLOT8  81920             // v8h slot-groups in wsw (655360 f16 / 8)
#define NOUT4   131072            // v4f groups in out (8192*64 f32 / 4)

// Wsw slot ((ks*4+nt)*64+lane)*8+j = W[k=ks*32+(lane>>4)*8+j][f=nt*16+(lane&15)]
__global__ __launch_bounds__(256) void prep_wsw(const float* __restrict__ cp,
                                                const float* __restrict__ w1,
                                                const float* __restrict__ w2,
                                                _Float16* __restrict__ wsw,
                                                float* __restrict__ out) {
    int tid = blockIdx.x * 256 + threadIdx.x;    // 0..131071 (512 blocks)
    if (tid < NSLOT8) {
        int lane = tid & 63;
        int rest = tid >> 6;
        int nt   = rest & 3;
        int ks   = rest >> 2;
        int kb   = ks * 32 + ((lane >> 4) << 3); // 8-aligned k base
        int f    = (nt << 4) + (lane & 15);
        int chunk = kb / 640;
        int klb   = kb - chunk * 640;
        v8h o;
        if (klb < 576) {
            int c  = (chunk << 2) + klb / 144;
            int rb = klb % 144;                  // 8-aligned, ij constant
            int ij = rb >> 4;
            float w = w1[f * 576 + c * 9 + ij];
            const v4f* cpp = (const v4f*)(cp + (size_t)f * 9216 + c * 144 + rb);
            v4f lo = cpp[0], hi = cpp[1];
#pragma unroll
            for (int j = 0; j < 4; ++j) {
                o[j]     = (_Float16)(w * lo[j]);
                o[j + 4] = (_Float16)(w * hi[j]);
            }
        } else {
            int i2 = klb - 576;                  // 8-aligned
            int c  = (chunk << 2) + (i2 >> 4);
            if ((i2 & 15) == 0) {                // ij = 0..7, all valid
#pragma unroll
                for (int j = 0; j < 8; ++j)
                    o[j] = (_Float16)w2[f * 576 + c * 9 + j];
            } else {                             // ij = 8..15, only ij==8 valid
#pragma unroll
                for (int j = 0; j < 8; ++j) o[j] = (_Float16)0.f;
                o[0] = (_Float16)w2[f * 576 + c * 9 + 8];
            }
        }
        ((v8h*)wsw)[tid] = o;
    }
    if (tid < NOUT4) ((v4f*)out)[tid] = (v4f){0.f, 0.f, 0.f, 0.f};
}

__device__ inline u32 h2u(float f) {
    union { _Float16 h; unsigned short u; } c;
    c.h = (_Float16)f;
    return (u32)c.u;
}

// Build the 8-f16 A-fragment for one (px, cl, ij, g-half): taps (1-fr)@idx,
// fr@idx+1 clipped to grid positions [g0, g0+8). x==0 (halo) gives taps
// (0.5,0.5)@7 -- matches the reference (padding taps DO contribute).
__device__ inline v8h spline_frag(float v, int g0) {
    float xc = fminf(fmaxf(v, -1.f), 1.f);
    float tt = (xc + 1.f) * 7.5f;
    int idx  = (int)tt;
    if (idx > 14) idx = 14;
    float fr = tt - (float)idx;
    int r0 = idx - g0;                 // tap0 at j=r0, tap1 at j=r0+1 (j in [0,8))
    u32 lo = h2u(1.f - fr);
    u32 hi = h2u(fr);
    u32 pair = lo | (hi << 16);
    int wq = r0 >> 1;                  // arith shift (r0 may be -1 -> wq=-1)
    int ro = r0 & 1;
    v4u w;
#pragma unroll
    for (int q = 0; q < 4; ++q) {
        u32 val = (q == wq) ? (ro ? (lo << 16) : pair)
                            : ((ro && q == wq + 1) ? hi : 0u);
        w[q] = val;
    }
    union { v4u u; v8h h; } cvt;
    cvt.u = w;
    return cvt.h;
}

// Silu fragment: 8 elems = silu(x[px, c, ij]) for ij = ijh..ijh+7 (ij<9 live).
__device__ inline v8h silu_frag(const float* __restrict__ xb, int xc,
                                int p, int pxq, int ijh) {
    v8h a;
#pragma unroll
    for (int j = 0; j < 8; ++j) {
        int ij = ijh + j;
        float sv = 0.f;
        if (ij < 9) {
            int di = (ij * 11) >> 5;           // ij/3 for ij in [0,8]
            int dj = ij - 3 * di;
            int row = p + di - 1;
            int col = pxq + dj - 1;
            float xv = ((unsigned)row < 32u && (unsigned)col < 32u)
                     ? xb[(row * 32 + col) * 64 + xc] : 0.f;
            sv = xv * __builtin_amdgcn_rcpf(1.f + __expf(-xv));
        }
        a[j] = (_Float16)sv;
    }
    return a;
}

// grid 768: kh = blk>>8 (chunk range {0-5,6-10,11-15}), rowid = blk&255 = (b,p).
// WG = 32 px (one image row). 4 waves split each chunk's 20 ksteps (5 each);
// each wave holds the full 32x64 fp32 accumulator; LDS reduce at the end, then
// atomicAdd into out (3 contenders/address, coalesced 64-lane bursts).
__global__ __launch_bounds__(256, 3) void kan_mfma(const float* __restrict__ x,
                                                   const _Float16* __restrict__ wsw,
                                                   float* __restrict__ out) {
    __shared__ __align__(16) float red[8320];   // [4][32][65] f32 reduce, 33 KB

    int blk   = blockIdx.x;
    int kh    = blk >> 8;
    int rowid = blk & 255;
    int b = rowid >> 5, p = rowid & 31;
    int t = threadIdx.x, wv = t >> 6, lane = t & 63;
    int m = lane & 15, kq = lane >> 4;

    const int chs[4] = {0, 6, 11, 16};
    int ch0 = chs[kh], ch1 = chs[kh + 1];

    const float* xb = x + (size_t)b * 65536;

    // ---- hoisted per-kstep metadata (chunk-invariant) ----
    // spline step: offA/offB = (row*32+col)*64 + cl (or -1 halo), g0s = grid
    // half offset {0,8}. silu step (kk>=576, wave-uniform): g0s = -(i2+1).
    int offA[5], offB[5], g0s[5];
#pragma unroll
    for (int s = 0; s < 5; ++s) {
        int kst = wv * 5 + s;
        int kk  = kst * 32 + kq * 8;
        if (kk < 576) {
            int cl = kk / 144;
            int rr = kk - cl * 144;
            int ij = rr >> 4;
            g0s[s] = rr & 15;                   // 0 or 8
            int di = (ij * 11) >> 5;
            int dj = ij - 3 * di;
            int row = p + di - 1;
            int c0  = m + dj - 1;
            int c1  = c0 + 16;
            bool okr = (unsigned)row < 32u;
            offA[s] = (okr && (unsigned)c0 < 32u) ? (row * 32 + c0) * 64 + cl : -1;
            offB[s] = (okr && (unsigned)c1 < 32u) ? (row * 32 + c1) * 64 + cl : -1;
        } else {
            g0s[s] = -(kk - 576) - 1;
            offA[s] = 0;
            offB[s] = 0;
        }
    }

    v4f z4 = (v4f){0.f, 0.f, 0.f, 0.f};
    v4f acc[2][4];
#pragma unroll
    for (int i = 0; i < 2; ++i)
#pragma unroll
        for (int n = 0; n < 4; ++n) acc[i][n] = z4;

    // ==================== barrier-free main loop ====================
    for (int gch = ch0; gch < ch1; ++gch) {
        const v8h* bp = (const v8h*)wsw + ((size_t)gch * 20 + wv * 5) * 256 + lane;
        int xc4 = gch * 4;
#pragma unroll
        for (int s = 0; s < 5; ++s) {
            v8h a0, a1;
            int g0 = g0s[s];
            if (g0 >= 0) {                      // wave-uniform branch
                float x0 = (offA[s] >= 0) ? xb[offA[s] + xc4] : 0.f;
                float x1 = (offB[s] >= 0) ? xb[offB[s] + xc4] : 0.f;
                a0 = spline_frag(x0, g0);
                a1 = spline_frag(x1, g0);
            } else {
                int i2  = -1 - g0;
                int cl  = i2 >> 4;
                int ijh = i2 & 15;
                a0 = silu_frag(xb, xc4 + cl, p, m, ijh);
                a1 = silu_frag(xb, xc4 + cl, p, m + 16, ijh);
            }
            v8h b0 = bp[s * 256];
            v8h b1 = bp[s * 256 + 64];
            v8h b2 = bp[s * 256 + 128];
            v8h b3 = bp[s * 256 + 192];
            acc[0][0] = __builtin_amdgcn_mfma_f32_16x16x32_f16(a0, b0, acc[0][0], 0, 0, 0);
            acc[0][1] = __builtin_amdgcn_mfma_f32_16x16x32_f16(a0, b1, acc[0][1], 0, 0, 0);
            acc[0][2] = __builtin_amdgcn_mfma_f32_16x16x32_f16(a0, b2, acc[0][2], 0, 0, 0);
            acc[0][3] = __builtin_amdgcn_mfma_f32_16x16x32_f16(a0, b3, acc[0][3], 0, 0, 0);
            acc[1][0] = __builtin_amdgcn_mfma_f32_16x16x32_f16(a1, b0, acc[1][0], 0, 0, 0);
            acc[1][1] = __builtin_amdgcn_mfma_f32_16x16x32_f16(a1, b1, acc[1][1], 0, 0, 0);
            acc[1][2] = __builtin_amdgcn_mfma_f32_16x16x32_f16(a1, b2, acc[1][2], 0, 0, 0);
            acc[1][3] = __builtin_amdgcn_mfma_f32_16x16x32_f16(a1, b3, acc[1][3], 0, 0, 0);
        }
    }

    // ---- 4-wave LDS reduction, then coalesced atomicAdd into out ----
#pragma unroll
    for (int mt = 0; mt < 2; ++mt)
#pragma unroll
        for (int nt = 0; nt < 4; ++nt)
#pragma unroll
            for (int r = 0; r < 4; ++r)
                red[wv * 2080 + (mt * 16 + kq * 4 + r) * 65 + nt * 16 + m] = acc[mt][nt][r];
    __syncthreads();
    int f = t & 63, pxg = t >> 6;
    float* op = out + (size_t)rowid * 2048 + f;
#pragma unroll
    for (int i = 0; i < 8; ++i) {
        int px = pxg * 8 + i;
        float s = red[px * 65 + f] + red[2080 + px * 65 + f]
                + red[4160 + px * 65 + f] + red[6240 + px * 65 + f];
        atomicAdd(op + px * 64, s);
    }
}

extern "C" void kernel_launch(void* const* d_in, const int* in_sizes, int n_in,
                              void* d_out, int out_size, void* d_ws, size_t ws_size,
                              hipStream_t stream) {
    const float* x  = (const float*)d_in[0];
    const float* cp = (const float*)d_in[1];
    const float* w1 = (const float*)d_in[2];
    const float* w2 = (const float*)d_in[3];
    _Float16* wsw = (_Float16*)d_ws;                       // 1.31 MB
    float*    outp = (float*)d_out;

    prep_wsw<<<512, 256, 0, stream>>>(cp, w1, w2, wsw, outp);
    kan_mfma<<<768, 256, 0, stream>>>(x, wsw, outp);
}

// Round 5
// 96.360 us; speedup vs baseline: 1.3507x; 1.3507x over previous
//
#include <hip/hip_runtime.h>

// KAN conv as densified GEMM: out[px,f] = sum_k Basis[px,k] * W[k,f]
//   px = (b,p,q) 8192, f = 64, K = 16 chunks x 640:
//   chunk kl in [0,576): spline (cl*144 + ij*16 + g), taps (1-fr)@idx, fr@idx+1
//   chunk kl in [576,640): silu at cl*16 + ij (ij<9), rest zero-pad (W rows 0)
// W pre-swizzled to MFMA 16x16x32 f16 B-fragment order. Basis built in LDS with
// self-clearing scatter. THIS REVISION: double-buffered basis, M-tile=16.
//   r3's [scatter | bar | MFMA | bar] lockstep (2 barriers/chunk) serialized
//   the phases (m233-style 2-phase stall). r4's register-build was worse
//   (latency-bound, 3.4x VALU). Now: tile = 16 px (half image row), basis
//   double-buffered 2x[16][648] f16 = 41.5 KB (same LDS, still 3 blocks/CU),
//   grid 1536. Per chunk: scatter(g+1)->buf[cur^1] and MFMA(g)<-buf[cur] are
//   ONE instruction stream, ONE barrier. ds_writes/ds_reads hit disjoint
//   buffers -> compiler interleaves; waves 2-3 (few scatter items) go straight
//   to MFMA. Self-clear tracked per buffer parity. Epilogue atomicAdds to out
//   (still 3 contenders/address). 2 dispatches, no partials.

typedef _Float16 v8h __attribute__((ext_vector_type(8)));
typedef float    v4f __attribute__((ext_vector_type(4)));

#define NSLOT8  81920             // v8h slot-groups in wsw (655360 f16 / 8)
#define NOUT4   131072            // v4f groups in out (8192*64 f32 / 4)
#define BUFH    10368             // f16 per basis buffer: 16*648

// Wsw slot ((ks*4+nt)*64+lane)*8+j = W[k=ks*32+(lane>>4)*8+j][f=nt*16+(lane&15)]
__global__ __launch_bounds__(256) void prep_wsw(const float* __restrict__ cp,
                                                const float* __restrict__ w1,
                                                const float* __restrict__ w2,
                                                _Float16* __restrict__ wsw,
                                                float* __restrict__ out) {
    int tid = blockIdx.x * 256 + threadIdx.x;    // 0..131071 (512 blocks)
    if (tid < NSLOT8) {
        int lane = tid & 63;
        int rest = tid >> 6;
        int nt   = rest & 3;
        int ks   = rest >> 2;
        int kb   = ks * 32 + ((lane >> 4) << 3); // 8-aligned k base
        int f    = (nt << 4) + (lane & 15);
        int chunk = kb / 640;
        int klb   = kb - chunk * 640;
        v8h o;
        if (klb < 576) {
            int c  = (chunk << 2) + klb / 144;
            int rb = klb % 144;                  // 8-aligned, ij constant
            int ij = rb >> 4;
            float w = w1[f * 576 + c * 9 + ij];
            const v4f* cpp = (const v4f*)(cp + (size_t)f * 9216 + c * 144 + rb);
            v4f lo = cpp[0], hi = cpp[1];
#pragma unroll
            for (int j = 0; j < 4; ++j) {
                o[j]     = (_Float16)(w * lo[j]);
                o[j + 4] = (_Float16)(w * hi[j]);
            }
        } else {
            int i2 = klb - 576;                  // 8-aligned
            int c  = (chunk << 2) + (i2 >> 4);
            if ((i2 & 15) == 0) {                // ij = 0..7, all valid
#pragma unroll
                for (int j = 0; j < 8; ++j)
                    o[j] = (_Float16)w2[f * 576 + c * 9 + j];
            } else {                             // ij = 8..15, only ij==8 valid
#pragma unroll
                for (int j = 0; j < 8; ++j) o[j] = (_Float16)0.f;
                o[0] = (_Float16)w2[f * 576 + c * 9 + 8];
            }
        }
        ((v8h*)wsw)[tid] = o;
    }
    if (tid < NOUT4) ((v4f*)out)[tid] = (v4f){0.f, 0.f, 0.f, 0.f};
}

// Scatter one (q16,ij) item's 4 channels from a prefetched v4f into a basis
// buffer. Self-clears the entries this item wrote to the SAME buffer 2 chunks
// ago (packed 4x8-bit in pk). Silu slot is a full overwrite (no clear needed).
__device__ inline void scatter4(v4f xv, _Float16* __restrict__ base,
                                int sbb, int silb, unsigned& pk, bool doClear,
                                bool active) {
    if (!active) return;
    _Float16* rp = base + sbb;
    _Float16* sp = base + silb;
    unsigned pp = pk, np = 0;
#pragma unroll
    for (int cl = 0; cl < 4; ++cl) {
        float v  = xv[cl];
        float xc = fminf(fmaxf(v, -1.f), 1.f);
        float tt = (xc + 1.f) * 7.5f;
        int idx  = (int)tt;
        if (idx > 14) idx = 14;
        float fr = tt - (float)idx;
        float sv = v * __builtin_amdgcn_rcpf(1.f + __expf(-v));
        _Float16* q = rp + cl * 144;
        if (doClear) {
            int pi = (pp >> (cl * 8)) & 255;
            q[pi]     = (_Float16)0.f;
            q[pi + 1] = (_Float16)0.f;
        }
        q[idx]     = (_Float16)(1.f - fr);
        q[idx + 1] = (_Float16)fr;
        sp[cl * 16] = (_Float16)sv;
        np |= (unsigned)idx << (cl * 8);
    }
    pk = np;
}

// grid 1536: kh = blk>>9 (chunk range {0-5,6-10,11-15}), id = blk&511:
// b = id>>6, p = (id>>1)&31, half = id&1 -> px tile = row p, cols half*16..+16.
// 4 waves split each chunk's 20 ksteps (5 each); each wave holds the full
// 16x64 fp32 accumulator; LDS reduce at the end, then atomicAdd into out.
__global__ __launch_bounds__(256, 3) void kan_mfma(const float* __restrict__ x,
                                                   const _Float16* __restrict__ wsw,
                                                   float* __restrict__ out) {
    __shared__ __align__(16) char smem[41472];
    _Float16* sb  = (_Float16*)smem;       // [2][16][648] f16 basis dbuf
    float*    red = (float*)smem;          // [4][16][65] f32 reduce, aliases sb

    int blk = blockIdx.x;
    int kh  = blk >> 9;
    int id  = blk & 511;
    int b = id >> 6, p = (id >> 1) & 31, half = id & 1;
    int t = threadIdx.x, wv = t >> 6, lane = t & 63;
    int m = lane & 15, kq = lane >> 4;

    const int chs[4] = {0, 6, 11, 16};
    int ch0 = chs[kh], ch1 = chs[kh + 1];

    const float* xb = x + (size_t)b * 65536;

    // ---- per-thread scatter geometry: 144 (q16,ij) items, 1 per thread ----
    bool active = t < 144;
    int xoff, sbb, silb;
    {
        int e   = active ? t : 0;
        int q16 = e / 9;
        int ij  = e - q16 * 9;
        int di  = ij / 3;
        int dj  = ij - di * 3;
        int row = p + di - 1;
        int col = half * 16 + q16 + dj - 1;
        bool ok = ((unsigned)row < 32u) && ((unsigned)col < 32u) && active;
        xoff = ok ? (row * 32 + col) * 64 : -1;   // sign = halo flag
        sbb  = q16 * 648 + ij * 16;
        silb = q16 * 648 + 576 + ij;
    }

    v4f z4 = (v4f){0.f, 0.f, 0.f, 0.f};
    v4f acc[4];
#pragma unroll
    for (int n = 0; n < 4; ++n) acc[n] = z4;

    // zero both basis buffers (41472 B = 2592 v4f)
    for (int i4 = t; i4 < 2592; i4 += 256) ((v4f*)sb)[i4] = z4;

    // prologue x prefetch for chunk ch0
    v4f vbuf = (xoff >= 0) ? *(const v4f*)(xb + xoff + ch0 * 4) : z4;
    unsigned pk0 = 0u, pk1 = 0u;

    __syncthreads();   // zeros visible

    // prologue scatter: chunk ch0 -> parity 0 (no clear), prefetch ch0+1
    scatter4(vbuf, sb, sbb, silb, pk0, false, active);
    if (ch0 + 1 < ch1)
        vbuf = (xoff >= 0) ? *(const v4f*)(xb + xoff + (ch0 + 1) * 4) : z4;
    __syncthreads();

    // ============ main loop: ONE barrier per chunk ============
    for (int g = ch0; g < ch1; ++g) {
        int cur = (g - ch0) & 1;
        // scatter(g+1) into the other buffer -- interleaves with MFMA below
        if (g + 1 < ch1) {
            if (cur == 0)
                scatter4(vbuf, sb + BUFH, sbb, silb, pk1, g > ch0, active);
            else
                scatter4(vbuf, sb, sbb, silb, pk0, g > ch0, active);
            if (g + 2 < ch1)
                vbuf = (xoff >= 0) ? *(const v4f*)(xb + xoff + (g + 2) * 4) : z4;
        }
        // MFMA(g) from buf[cur]: 20 ksteps, this wave takes 5
        const _Float16* ap = sb + cur * BUFH + m * 648 + (wv * 5) * 32 + kq * 8;
        const v8h* bp = (const v8h*)wsw + ((size_t)g * 20 + wv * 5) * 256 + lane;
#pragma unroll
        for (int s = 0; s < 5; ++s) {
            v8h a  = *(const v8h*)(ap + s * 32);
            v8h b0 = bp[s * 256];
            v8h b1 = bp[s * 256 + 64];
            v8h b2 = bp[s * 256 + 128];
            v8h b3 = bp[s * 256 + 192];
            acc[0] = __builtin_amdgcn_mfma_f32_16x16x32_f16(a, b0, acc[0], 0, 0, 0);
            acc[1] = __builtin_amdgcn_mfma_f32_16x16x32_f16(a, b1, acc[1], 0, 0, 0);
            acc[2] = __builtin_amdgcn_mfma_f32_16x16x32_f16(a, b2, acc[2], 0, 0, 0);
            acc[3] = __builtin_amdgcn_mfma_f32_16x16x32_f16(a, b3, acc[3], 0, 0, 0);
        }
        __syncthreads();
    }

    // ---- 4-wave LDS reduction, then coalesced atomicAdd into out ----
#pragma unroll
    for (int nt = 0; nt < 4; ++nt)
#pragma unroll
        for (int r = 0; r < 4; ++r)
            red[wv * 1040 + (kq * 4 + r) * 65 + nt * 16 + m] = acc[nt][r];
    __syncthreads();
    int f = t & 63, pxg = t >> 6;            // pxg in [0,4)
    float* op = out + ((size_t)(b * 32 + p) * 32 + half * 16) * 64 + f;
#pragma unroll
    for (int i = 0; i < 4; ++i) {
        int px = pxg * 4 + i;
        float s = red[px * 65 + f] + red[1040 + px * 65 + f]
                + red[2080 + px * 65 + f] + red[3120 + px * 65 + f];
        atomicAdd(op + px * 64, s);
    }
}

extern "C" void kernel_launch(void* const* d_in, const int* in_sizes, int n_in,
                              void* d_out, int out_size, void* d_ws, size_t ws_size,
                              hipStream_t stream) {
    const float* x  = (const float*)d_in[0];
    const float* cp = (const float*)d_in[1];
    const float* w1 = (const float*)d_in[2];
    const float* w2 = (const float*)d_in[3];
    _Float16* wsw = (_Float16*)d_ws;                       // 1.31 MB
    float*    outp = (float*)d_out;

    prep_wsw<<<512, 256, 0, stream>>>(cp, w1, w2, wsw, outp);
    kan_mfma<<<1536, 256, 0, stream>>>(x, wsw, outp);
}

// Round 6
// 83.004 us; speedup vs baseline: 1.5681x; 1.1609x over previous
//
#include <hip/hip_runtime.h>

// KAN conv as densified GEMM: out[px,f] = sum_k Basis[px,k] * W[k,f]
//   px = (b,p,q) 8192, f = 64, K = 16 chunks x 640:
//   chunk kl in [0,576): spline (cl*144 + ij*16 + g), taps (1-fr)@idx, fr@idx+1
//   chunk kl in [576,640): silu at cl*16 + ij (ij<9), rest zero-pad (W rows 0)
// W pre-swizzled to MFMA 16x16x32 f16 B-fragment order. Basis in LDS with
// self-clearing scatter. THIS REVISION: 4 blocks/CU via XOR-swizzled basis.
//   r5 lesson: B-L2-traffic scales with 1/M-tile -> keep M=32 (328 MB floor).
//   Stall-hider that works here is co-resident-block overlap (not intra-stream
//   dbuf). So: basis stride 648->640 (40960 B exactly; 4x40960 = full 160 KiB)
//   with XOR bank-swizzle phys = row*1280 + (intra ^ ((row&7)<<4)) applied to
//   BOTH scatter writes and MFMA reads (conflict-free b128: 8 lanes per 4-bank
//   group = structural minimum). Grid 1024 = 4-way K-split (4 chunks each,
//   balanced) = 4 blocks/CU = 16 waves/CU. Scatter rebalanced 72 items/wave.
//   Epilogue atomicAdds into out (4 contenders). 2 dispatches, no partials.

typedef _Float16 v8h __attribute__((ext_vector_type(8)));
typedef float    v4f __attribute__((ext_vector_type(4)));

#define NSLOT8  81920             // v8h slot-groups in wsw (655360 f16 / 8)
#define NOUT4   131072            // v4f groups in out (8192*64 f32 / 4)

// Wsw slot ((ks*4+nt)*64+lane)*8+j = W[k=ks*32+(lane>>4)*8+j][f=nt*16+(lane&15)]
__global__ __launch_bounds__(256) void prep_wsw(const float* __restrict__ cp,
                                                const float* __restrict__ w1,
                                                const float* __restrict__ w2,
                                                _Float16* __restrict__ wsw,
                                                float* __restrict__ out) {
    int tid = blockIdx.x * 256 + threadIdx.x;    // 0..131071 (512 blocks)
    if (tid < NSLOT8) {
        int lane = tid & 63;
        int rest = tid >> 6;
        int nt   = rest & 3;
        int ks   = rest >> 2;
        int kb   = ks * 32 + ((lane >> 4) << 3); // 8-aligned k base
        int f    = (nt << 4) + (lane & 15);
        int chunk = kb / 640;
        int klb   = kb - chunk * 640;
        v8h o;
        if (klb < 576) {
            int c  = (chunk << 2) + klb / 144;
            int rb = klb % 144;                  // 8-aligned, ij constant
            int ij = rb >> 4;
            float w = w1[f * 576 + c * 9 + ij];
            const v4f* cpp = (const v4f*)(cp + (size_t)f * 9216 + c * 144 + rb);
            v4f lo = cpp[0], hi = cpp[1];
#pragma unroll
            for (int j = 0; j < 4; ++j) {
                o[j]     = (_Float16)(w * lo[j]);
                o[j + 4] = (_Float16)(w * hi[j]);
            }
        } else {
            int i2 = klb - 576;                  // 8-aligned
            int c  = (chunk << 2) + (i2 >> 4);
            if ((i2 & 15) == 0) {                // ij = 0..7, all valid
#pragma unroll
                for (int j = 0; j < 8; ++j)
                    o[j] = (_Float16)w2[f * 576 + c * 9 + j];
            } else {                             // ij = 8..15, only ij==8 valid
#pragma unroll
                for (int j = 0; j < 8; ++j) o[j] = (_Float16)0.f;
                o[0] = (_Float16)w2[f * 576 + c * 9 + 8];
            }
        }
        ((v8h*)wsw)[tid] = o;
    }
    if (tid < NOUT4) ((v4f*)out)[tid] = (v4f){0.f, 0.f, 0.f, 0.f};
}

// grid 1024: kh = blk>>8 (chunks kh*4..kh*4+4), rowid = blk&255 = (b,p).
// WG = 32 px (one image row). 4 waves split each chunk's 20 ksteps (5 each);
// each wave holds the full 32x64 fp32 accumulator; LDS reduce at the end,
// then atomicAdd into out (4 contenders/address, coalesced 64-lane bursts).
// Basis layout: row px (0..31), 640 f16 = 1280 B/row; physical byte =
// row*1280 + (intra ^ ((row&7)<<4)). 40960 B total -> 4 blocks/CU.
__global__ __launch_bounds__(256, 4) void kan_mfma(const float* __restrict__ x,
                                                   const _Float16* __restrict__ wsw,
                                                   float* __restrict__ out) {
    __shared__ __align__(16) char smem[40960];
    float* red = (float*)smem;             // [4][32][65] f32 reduce (33280 B)

    int blk   = blockIdx.x;
    int kh    = blk >> 8;                  // 0..3
    int rowid = blk & 255;
    int b = rowid >> 5, p = rowid & 31;
    int t = threadIdx.x, wv = t >> 6, lane = t & 63;
    int m = lane & 15, kq = lane >> 4;

    int ch0 = kh * 4, ch1 = ch0 + 4;
    const float* xb = x + (size_t)b * 65536;

    // ---- scatter geometry: 288 (q,ij) items, 72 per wave ----
    // it0: e = wv*72 + lane (all lanes); it1: e = wv*72 + 64 + lane (lane<8)
    int xoff[2], sbase[2], smask[2], ijb[2];
    bool act[2];
#pragma unroll
    for (int it = 0; it < 2; ++it) {
        bool a = (it == 0) || (lane < 8);
        int e  = a ? (wv * 72 + it * 64 + lane) : 0;
        int q  = e / 9;
        int ij = e - q * 9;
        int di = ij / 3;
        int dj = ij - di * 3;
        int row = p + di - 1;
        int col = q + dj - 1;
        bool ok = ((unsigned)row < 32u) && ((unsigned)col < 32u) && a;
        act[it]   = a;
        xoff[it]  = ok ? (row * 32 + col) * 64 : -1;   // sign = halo flag
        sbase[it] = q * 1280;                          // row byte base
        smask[it] = (q & 7) << 4;                      // XOR swizzle mask
        ijb[it]   = ij * 32;                           // ij*16 slots * 2 B
    }

    v4f z4 = (v4f){0.f, 0.f, 0.f, 0.f};
    v4f acc[2][4];
#pragma unroll
    for (int i = 0; i < 2; ++i)
#pragma unroll
        for (int n = 0; n < 4; ++n) acc[i][n] = z4;

    // zero basis (40960 B = 2560 v4f)
    for (int i4 = t; i4 < 2560; i4 += 256) ((v4f*)smem)[i4] = z4;

    // prologue x prefetch for first chunk
    v4f vbuf[2];
#pragma unroll
    for (int it = 0; it < 2; ++it)
        vbuf[it] = (xoff[it] >= 0) ? *(const v4f*)(xb + xoff[it] + ch0 * 4) : z4;
    unsigned pk[2] = {0u, 0u};

    __syncthreads();   // zeros visible

    for (int gch = ch0; gch < ch1; ++gch) {
        // ---- scatter: 4 channels per item; swizzled 2-byte writes ----
#pragma unroll
        for (int it = 0; it < 2; ++it) {
            if (act[it]) {
                v4f xv = vbuf[it];
                char* rowp = smem + sbase[it];
                int mask = smask[it];
                int jb   = ijb[it];
                unsigned pp = pk[it], np = 0;
#pragma unroll
                for (int cl = 0; cl < 4; ++cl) {
                    float v  = xv[cl];
                    float xc = fminf(fmaxf(v, -1.f), 1.f);
                    float tt = (xc + 1.f) * 7.5f;
                    int idx  = (int)tt;
                    if (idx > 14) idx = 14;
                    float fr = tt - (float)idx;
                    float sv = v * __builtin_amdgcn_rcpf(1.f + __expf(-v));
                    int sb0 = cl * 288 + jb;           // spline block byte base
                    if (gch > ch0) {                   // self-clear prev taps
                        int pb = sb0 + (int)((pp >> (cl * 8)) & 255) * 2;
                        *(_Float16*)(rowp + (pb ^ mask))       = (_Float16)0.f;
                        *(_Float16*)(rowp + ((pb + 2) ^ mask)) = (_Float16)0.f;
                    }
                    int wb = sb0 + idx * 2;
                    *(_Float16*)(rowp + (wb ^ mask))       = (_Float16)(1.f - fr);
                    *(_Float16*)(rowp + ((wb + 2) ^ mask)) = (_Float16)fr;
                    *(_Float16*)(rowp + ((1152 + cl * 32 + (jb >> 4)) ^ mask))
                        = (_Float16)sv;                // silu slot (overwrite)
                    np |= (unsigned)idx << (cl * 8);
                }
                pk[it] = np;
            }
        }
        __syncthreads();
        // prefetch next chunk's x (drains at the next barrier, under MFMA)
        if (gch + 1 < ch1) {
#pragma unroll
            for (int it = 0; it < 2; ++it)
                vbuf[it] = (xoff[it] >= 0)
                         ? *(const v4f*)(xb + xoff[it] + (gch + 1) * 4) : z4;
        }
        // ---- MFMA: 20 ksteps, this wave takes 5; swizzled A reads ----
        const v8h* bp = (const v8h*)wsw + ((size_t)gch * 20 + wv * 5) * 256 + lane;
        int mbase = m * 1280;
        int mm    = (m & 7) << 4;
#pragma unroll
        for (int s = 0; s < 5; ++s) {
            int kx = (((wv * 5 + s) * 64) + (kq * 16)) ^ mm;
            v8h a0 = *(const v8h*)(smem + mbase + kx);
            v8h a1 = *(const v8h*)(smem + mbase + 20480 + kx);   // row m+16
            v8h b0 = bp[s * 256];
            v8h b1 = bp[s * 256 + 64];
            v8h b2 = bp[s * 256 + 128];
            v8h b3 = bp[s * 256 + 192];
            acc[0][0] = __builtin_amdgcn_mfma_f32_16x16x32_f16(a0, b0, acc[0][0], 0, 0, 0);
            acc[0][1] = __builtin_amdgcn_mfma_f32_16x16x32_f16(a0, b1, acc[0][1], 0, 0, 0);
            acc[0][2] = __builtin_amdgcn_mfma_f32_16x16x32_f16(a0, b2, acc[0][2], 0, 0, 0);
            acc[0][3] = __builtin_amdgcn_mfma_f32_16x16x32_f16(a0, b3, acc[0][3], 0, 0, 0);
            acc[1][0] = __builtin_amdgcn_mfma_f32_16x16x32_f16(a1, b0, acc[1][0], 0, 0, 0);
            acc[1][1] = __builtin_amdgcn_mfma_f32_16x16x32_f16(a1, b1, acc[1][1], 0, 0, 0);
            acc[1][2] = __builtin_amdgcn_mfma_f32_16x16x32_f16(a1, b2, acc[1][2], 0, 0, 0);
            acc[1][3] = __builtin_amdgcn_mfma_f32_16x16x32_f16(a1, b3, acc[1][3], 0, 0, 0);
        }
        __syncthreads();
    }

    // ---- 4-wave LDS reduction, then coalesced atomicAdd into out ----
#pragma unroll
    for (int mt = 0; mt < 2; ++mt)
#pragma unroll
        for (int nt = 0; nt < 4; ++nt)
#pragma unroll
            for (int r = 0; r < 4; ++r)
                red[wv * 2080 + (mt * 16 + kq * 4 + r) * 65 + nt * 16 + m] = acc[mt][nt][r];
    __syncthreads();
    int f = t & 63, pxg = t >> 6;
    float* op = out + (size_t)rowid * 2048 + f;
#pragma unroll
    for (int i = 0; i < 8; ++i) {
        int px = pxg * 8 + i;
        float s = red[px * 65 + f] + red[2080 + px * 65 + f]
                + red[4160 + px * 65 + f] + red[6240 + px * 65 + f];
        atomicAdd(op + px * 64, s);
    }
}

extern "C" void kernel_launch(void* const* d_in, const int* in_sizes, int n_in,
                              void* d_out, int out_size, void* d_ws, size_t ws_size,
                              hipStream_t stream) {
    const float* x  = (const float*)d_in[0];
    const float* cp = (const float*)d_in[1];
    const float* w1 = (const float*)d_in[2];
    const float* w2 = (const float*)d_in[3];
    _Float16* wsw = (_Float16*)d_ws;                       // 1.31 MB
    float*    outp = (float*)d_out;

    prep_wsw<<<512, 256, 0, stream>>>(cp, w1, w2, wsw, outp);
    kan_mfma<<<1024, 256, 0, stream>>>(x, wsw, outp);
}